// Round 4
// baseline (241.618 us; speedup 1.0000x reference)
//
#include <hip/hip_runtime.h>
#include <math.h>

#define NPTS 65536
#define NV 6890
#define NVP 6912            // 8 slices x 864
#define NSLICE 8
#define SLICE_LEN 864
#define PTS_PER_BLK 64
#define NJ 24
#define CHUNK 8             // verts per prefetch chunk (8 x 16B = 32 SGPRs/buffer)
#define VPAD 64             // extra padded verts for prefetch overrun

// Kernel 0: pack per-vertex (x, y, z, ||v||^2_f32) into d_ws as float4.
__global__ void prep_verts_k(const float* __restrict__ verts, float4* __restrict__ vp) {
    int j = blockIdx.x * blockDim.x + threadIdx.x;
    if (j >= NVP + VPAD) return;
    if (j < NV) {
        float x = verts[3 * j + 0];
        float y = verts[3 * j + 1];
        float z = verts[3 * j + 2];
        double n64 = (double)x * x + (double)y * y + (double)z * z;
        vp[j] = make_float4(x, y, z, (float)n64);
    } else {
        vp[j] = make_float4(0.0f, 0.0f, 0.0f, 1e30f);  // sentinel: never selected
    }
}

__launch_bounds__(512)
__global__ void smplnn_main(const float* __restrict__ xyz,
                            const float* __restrict__ rot,
                            const float4* __restrict__ vp_all,
                            const float* __restrict__ sw,
                            const float* __restrict__ bt,
                            float* __restrict__ out) {
    __shared__ float bts[NJ * 16];
    __shared__ double sbest[512];
    __shared__ int sidx[512];

    const int tid = threadIdx.x;
    const int pl = tid & 63;
    const int slice = __builtin_amdgcn_readfirstlane(tid >> 6);
    const int i = blockIdx.x * PTS_PER_BLK + pl;

    const float xf = xyz[3 * i + 0];
    const float yf = xyz[3 * i + 1];
    const float zf = xyz[3 * i + 2];
    const float nxf = -2.0f * xf, nyf = -2.0f * yf, nzf = -2.0f * zf;

    // |s_f32 - s_f64| <= E = 0.5*ulp(NMAX) + 1.5*ulp(T),  T >= any partial sum.
    // coords bounded by 6 (6-sigma), NMAX = 3*36 = 108. margin2 = 2E.
    const float T = fmaf(12.0f, fabsf(xf) + fabsf(yf) + fabsf(zf), 108.0f);
    const float margin2 = fmaf(T, 7.2e-7f, 1.6e-5f);

    const float4* __restrict__ vp = vp_all + slice * SLICE_LEN;

    float b1 = 1e30f, b2 = 1e30f;
    int i1 = 0;

    // software-pipelined f32 scan (wave-uniform SMEM stream, ping-pong chunks)
    float4 A[CHUNK], B[CHUNK];
    #pragma unroll
    for (int u = 0; u < CHUNK; ++u) A[u] = vp[u];

    const int NCH = SLICE_LEN / CHUNK;  // 108 (even)
    for (int c = 0; c < NCH; c += 2) {
        #pragma unroll
        for (int u = 0; u < CHUNK; ++u) B[u] = vp[(c + 1) * CHUNK + u];
        #pragma unroll
        for (int u = 0; u < CHUNK; ++u) {
            float4 v = A[u];
            float s = fmaf(v.x, nxf, fmaf(v.y, nyf, fmaf(v.z, nzf, v.w)));
            b2 = fminf(b2, fmaxf(s, b1));
            if (s < b1) i1 = c * CHUNK + u;
            b1 = fminf(b1, s);
        }
        #pragma unroll
        for (int u = 0; u < CHUNK; ++u) A[u] = vp[(c + 2) * CHUNK + u];  // overruns 16 verts on last iter: padded
        #pragma unroll
        for (int u = 0; u < CHUNK; ++u) {
            float4 v = B[u];
            float s = fmaf(v.x, nxf, fmaf(v.y, nyf, fmaf(v.z, nzf, v.w)));
            b2 = fminf(b2, fmaxf(s, b1));
            if (s < b1) i1 = (c + 1) * CHUNK + u;
            b1 = fminf(b1, s);
        }
    }

    // Exact f64 value (and exact argmin when the f32 gap is inside the margin)
    const double nx64 = -2.0 * (double)xf;
    const double ny64 = -2.0 * (double)yf;
    const double nz64 = -2.0 * (double)zf;

    int bi;
    double sb;
    const bool uncertain = (b2 - b1) <= margin2;
    if (__any(uncertain)) {
        // exact rescan of the slice; f64 evaluated only inside the margin zone
        double bb = 1e300;
        int bj = 0;
        const float zlim = b1 + margin2;
        for (int j = 0; j < SLICE_LEN; ++j) {
            float4 v = vp[j];
            float s32 = fmaf(v.x, nxf, fmaf(v.y, nyf, fmaf(v.z, nzf, v.w)));
            if (__any(s32 <= zlim)) {
                // sentinel pads have s32 = 1e30 -> can never enter any lane's zone
                double vx = v.x, vy = v.y, vz = v.z;
                double n64 = vx * vx + vy * vy + vz * vz;
                double s64 = fma(vx, nx64, fma(vy, ny64, fma(vz, nz64, n64)));
                if (s64 < bb) { bb = s64; bj = j; }
            }
        }
        bi = slice * SLICE_LEN + bj;
        sb = bb;
    } else {
        bi = slice * SLICE_LEN + i1;
        float4 v = vp[i1];  // divergent gather, L2-hot
        double vx = v.x, vy = v.y, vz = v.z;
        double n64 = vx * vx + vy * vy + vz * vz;
        sb = fma(vx, nx64, fma(vy, ny64, fma(vz, nz64, n64)));
    }

    // stage bone transforms + share per-slice results (single barrier)
    for (int t = tid; t < NJ * 16; t += 512) bts[t] = bt[t];
    sbest[tid] = sb;
    sidx[tid] = bi;
    __syncthreads();

    if (slice != 0) return;

    double best = sb;
    #pragma unroll
    for (int s2 = 1; s2 < NSLICE; ++s2) {
        double b = sbest[pl + 64 * s2];
        int ix = sidx[pl + 64 * s2];
        if (b < best) { best = b; bi = ix; }
    }

    // T_fwd = W[bi] @ bone_transforms(24x16)
    const float* W = &sw[bi * NJ];
    float Tm[16];
    #pragma unroll
    for (int r = 0; r < 16; ++r) Tm[r] = 0.0f;
    #pragma unroll
    for (int k = 0; k < NJ; ++k) {
        float w = W[k];
        #pragma unroll
        for (int r = 0; r < 16; ++r) Tm[r] = fmaf(w, bts[16 * k + r], Tm[r]);
    }

    // x_bar = T[:3,:3] @ x + T[:3,3]
    float xb0 = Tm[0] * xf + Tm[1] * yf + Tm[2]  * zf + Tm[3];
    float xb1 = Tm[4] * xf + Tm[5] * yf + Tm[6]  * zf + Tm[7];
    float xb2 = Tm[8] * xf + Tm[9] * yf + Tm[10] * zf + Tm[11];

    // rotation_hat from quaternion (r,x,y,z), normalized
    float qr = rot[4 * i + 0];
    float qx = rot[4 * i + 1];
    float qy = rot[4 * i + 2];
    float qz = rot[4 * i + 3];
    float inv = 1.0f / sqrtf(qr * qr + qx * qx + qy * qy + qz * qz);
    qr *= inv; qx *= inv; qy *= inv; qz *= inv;

    float Rh[9];
    Rh[0] = 1.0f - 2.0f * (qy * qy + qz * qz);
    Rh[1] = 2.0f * (qx * qy - qr * qz);
    Rh[2] = 2.0f * (qx * qz + qr * qy);
    Rh[3] = 2.0f * (qx * qy + qr * qz);
    Rh[4] = 1.0f - 2.0f * (qx * qx + qz * qz);
    Rh[5] = 2.0f * (qy * qz - qr * qx);
    Rh[6] = 2.0f * (qx * qz - qr * qy);
    Rh[7] = 2.0f * (qy * qz + qr * qx);
    Rh[8] = 1.0f - 2.0f * (qx * qx + qy * qy);

    // rotation_bar = T[:3,:3] @ Rh
    float RB[9];
    #pragma unroll
    for (int r = 0; r < 3; ++r) {
        #pragma unroll
        for (int c = 0; c < 3; ++c) {
            RB[3 * r + c] = Tm[4 * r + 0] * Rh[c]
                          + Tm[4 * r + 1] * Rh[3 + c]
                          + Tm[4 * r + 2] * Rh[6 + c];
        }
    }

    // outputs: x_bar [NPTS*3] | rotation_bar [NPTS*9] | T_fwd [NPTS*16]
    out[3 * i + 0] = xb0;
    out[3 * i + 1] = xb1;
    out[3 * i + 2] = xb2;
    float* ob = out + 3 * NPTS + 9 * i;
    #pragma unroll
    for (int k = 0; k < 9; ++k) ob[k] = RB[k];
    float* ot = out + 12 * NPTS + 16 * i;
    #pragma unroll
    for (int k = 0; k < 16; ++k) ot[k] = Tm[k];
}

extern "C" void kernel_launch(void* const* d_in, const int* in_sizes, int n_in,
                              void* d_out, int out_size, void* d_ws, size_t ws_size,
                              hipStream_t stream) {
    const float* xyz   = (const float*)d_in[0];
    const float* rot   = (const float*)d_in[1];
    const float* verts = (const float*)d_in[2];
    const float* sw    = (const float*)d_in[3];
    const float* bt    = (const float*)d_in[4];
    float* out = (float*)d_out;

    float4* vp = (float4*)d_ws;
    prep_verts_k<<<(NVP + VPAD + 255) / 256, 256, 0, stream>>>(verts, vp);
    smplnn_main<<<NPTS / PTS_PER_BLK, 512, 0, stream>>>(xyz, rot, vp, sw, bt, out);
}

// Round 5
// 205.897 us; speedup vs baseline: 1.1735x; 1.1735x over previous
//
#include <hip/hip_runtime.h>
#include <math.h>

#define NPTS 65536
#define NV 6890
#define NT 432               // vertex tiles of 16 (432*16 = 6912 >= 6890)
#define NJ 24
#define WAVES_PER_BLK 4
#define PTS_PER_WAVE 32
#define PTS_PER_BLK (WAVES_PER_BLK * PTS_PER_WAVE)   // 128
#define NBLK (NPTS / PTS_PER_BLK)                    // 512

typedef double f64x4 __attribute__((ext_vector_type(4)));

// Prep: pack the B-fragment stream for v_mfma_f64_16x16x4_f64.
// frag[t*64 + l] = component (l>>4) of vertex (t*16 + (l&15));
// components: 0..2 = x,y,z (f64), 3 = ||v||^2 (exact f64 from f32 coords).
// Sentinel verts (j >= NV): (0,0,0,1e300) -> score 1e300, never selected.
__global__ void prep_frags_k(const float* __restrict__ verts, double* __restrict__ bf) {
    int e = blockIdx.x * blockDim.x + threadIdx.x;
    if (e >= NT * 64) return;
    int l = e & 63;
    int t = e >> 6;
    int j = t * 16 + (l & 15);
    int k = l >> 4;
    double val;
    if (j < NV) {
        if (k < 3) {
            val = (double)verts[3 * j + k];
        } else {
            double x = (double)verts[3 * j + 0];
            double y = (double)verts[3 * j + 1];
            double z = (double)verts[3 * j + 2];
            val = x * x + y * y + z * z;
        }
    } else {
        val = (k == 3) ? 1e300 : 0.0;
    }
    bf[e] = val;
}

__launch_bounds__(256)
__global__ void smplnn_main(const float* __restrict__ xyz,
                            const float* __restrict__ rot,
                            const double* __restrict__ bf,
                            const float* __restrict__ sw,
                            const float* __restrict__ bt,
                            float* __restrict__ out) {
    // per-wave slot boards: [wave][set][row][col]
    __shared__ double smin[WAVES_PER_BLK][2][16][16];
    __shared__ int    sidv[WAVES_PER_BLK][2][16][16];

    const int tid  = threadIdx.x;
    const int lane = tid & 63;
    const int wave = tid >> 6;
    const int r = lane & 15;           // M/N index within fragment
    const int k = lane >> 4;           // K index (0..3)
    const int pbase = blockIdx.x * PTS_PER_BLK + wave * PTS_PER_WAVE;

    // A fragments: A[i][k] = (-2x_i, -2y_i, -2z_i, 1.0), i = lane&15
    double a0 = (k == 3) ? 1.0 : -2.0 * (double)xyz[3 * (pbase + r) + k];
    double a1 = (k == 3) ? 1.0 : -2.0 * (double)xyz[3 * (pbase + 16 + r) + k];

    const f64x4 zero = {0.0, 0.0, 0.0, 0.0};

    // Layout self-calibration: D = row-index and D = col-index, so the
    // (lane,reg)->(row,col) mapping of the D fragment never has to be assumed.
    double ar  = (k == 3) ? (double)r : 0.0;  // A[i][3] = i  /  B[3][j] = j
    double one = (k == 3) ? 1.0 : 0.0;        // A[i][3] = 1  /  B[3][j] = 1
    f64x4 drow = __builtin_amdgcn_mfma_f64_16x16x4f64(ar, one, zero, 0, 0, 0);
    f64x4 dcol = __builtin_amdgcn_mfma_f64_16x16x4f64(one, ar, zero, 0, 0, 0);
    int rowid[4], colid[4];
    #pragma unroll
    for (int v = 0; v < 4; ++v) { rowid[v] = (int)drow[v]; colid[v] = (int)dcol[v]; }

    double m0[4], m1[4];
    int t0[4], t1[4];
    #pragma unroll
    for (int v = 0; v < 4; ++v) { m0[v] = 1e301; m1[v] = 1e301; t0[v] = 0; t1[v] = 0; }

    // scan all vertex tiles: s = -2 x.v + ||v||^2, exact f64 via MFMA
    const double* bl = bf + lane;
    double bcur = bl[0];
    double bnx  = bl[64];
    #pragma unroll 2
    for (int t = 0; t < NT; ++t) {
        int tp = t + 2; if (tp > NT - 1) tp = NT - 1;   // clamped prefetch
        double bpf = bl[(size_t)tp * 64];
        f64x4 d0 = __builtin_amdgcn_mfma_f64_16x16x4f64(a0, bcur, zero, 0, 0, 0);
        f64x4 d1 = __builtin_amdgcn_mfma_f64_16x16x4f64(a1, bcur, zero, 0, 0, 0);
        #pragma unroll
        for (int v = 0; v < 4; ++v) {
            if (d0[v] < m0[v]) { m0[v] = d0[v]; t0[v] = t; }
            if (d1[v] < m1[v]) { m1[v] = d1[v]; t1[v] = t; }
        }
        bcur = bnx; bnx = bpf;
    }

    // publish slots (strict < kept earliest tile; j = tile*16 + col)
    #pragma unroll
    for (int v = 0; v < 4; ++v) {
        smin[wave][0][rowid[v]][colid[v]] = m0[v];
        sidv[wave][0][rowid[v]][colid[v]] = t0[v] * 16 + colid[v];
        smin[wave][1][rowid[v]][colid[v]] = m1[v];
        sidv[wave][1][rowid[v]][colid[v]] = t1[v] * 16 + colid[v];
    }
    __syncthreads();

    if (lane >= 32) return;

    // epilogue: lane 0..31 -> point (set = lane>>4, row = lane&15)
    const int set  = lane >> 4;
    const int prow = lane & 15;
    const int i = pbase + set * 16 + prow;

    double best = smin[wave][set][prow][0];
    int bi = sidv[wave][set][prow][0];
    #pragma unroll
    for (int c = 1; c < 16; ++c) {
        double bv = smin[wave][set][prow][c];
        int bj = sidv[wave][set][prow][c];
        if (bv < best || (bv == best && bj < bi)) { best = bv; bi = bj; }
    }

    const float xf = xyz[3 * i + 0];
    const float yf = xyz[3 * i + 1];
    const float zf = xyz[3 * i + 2];

    // T_fwd = W[bi] @ bone_transforms(24x16)
    const float* W = &sw[bi * NJ];
    float Tm[16];
    #pragma unroll
    for (int q = 0; q < 16; ++q) Tm[q] = 0.0f;
    #pragma unroll
    for (int kk = 0; kk < NJ; ++kk) {
        float w = W[kk];
        #pragma unroll
        for (int q = 0; q < 16; ++q) Tm[q] = fmaf(w, bt[16 * kk + q], Tm[q]);
    }

    // x_bar = T[:3,:3] @ x + T[:3,3]
    float xb0 = Tm[0] * xf + Tm[1] * yf + Tm[2]  * zf + Tm[3];
    float xb1 = Tm[4] * xf + Tm[5] * yf + Tm[6]  * zf + Tm[7];
    float xb2 = Tm[8] * xf + Tm[9] * yf + Tm[10] * zf + Tm[11];

    // rotation_hat from quaternion (r,x,y,z), normalized
    float qr = rot[4 * i + 0];
    float qx = rot[4 * i + 1];
    float qy = rot[4 * i + 2];
    float qz = rot[4 * i + 3];
    float inv = 1.0f / sqrtf(qr * qr + qx * qx + qy * qy + qz * qz);
    qr *= inv; qx *= inv; qy *= inv; qz *= inv;

    float Rh[9];
    Rh[0] = 1.0f - 2.0f * (qy * qy + qz * qz);
    Rh[1] = 2.0f * (qx * qy - qr * qz);
    Rh[2] = 2.0f * (qx * qz + qr * qy);
    Rh[3] = 2.0f * (qx * qy + qr * qz);
    Rh[4] = 1.0f - 2.0f * (qx * qx + qz * qz);
    Rh[5] = 2.0f * (qy * qz - qr * qx);
    Rh[6] = 2.0f * (qx * qz - qr * qy);
    Rh[7] = 2.0f * (qy * qz + qr * qx);
    Rh[8] = 1.0f - 2.0f * (qx * qx + qy * qy);

    // rotation_bar = T[:3,:3] @ Rh
    float RB[9];
    #pragma unroll
    for (int rr = 0; rr < 3; ++rr) {
        #pragma unroll
        for (int cc = 0; cc < 3; ++cc) {
            RB[3 * rr + cc] = Tm[4 * rr + 0] * Rh[cc]
                            + Tm[4 * rr + 1] * Rh[3 + cc]
                            + Tm[4 * rr + 2] * Rh[6 + cc];
        }
    }

    // outputs: x_bar [NPTS*3] | rotation_bar [NPTS*9] | T_fwd [NPTS*16]
    out[3 * i + 0] = xb0;
    out[3 * i + 1] = xb1;
    out[3 * i + 2] = xb2;
    float* ob = out + 3 * NPTS + 9 * i;
    #pragma unroll
    for (int q = 0; q < 9; ++q) ob[q] = RB[q];
    float* ot = out + 12 * NPTS + 16 * i;
    #pragma unroll
    for (int q = 0; q < 16; ++q) ot[q] = Tm[q];
}

extern "C" void kernel_launch(void* const* d_in, const int* in_sizes, int n_in,
                              void* d_out, int out_size, void* d_ws, size_t ws_size,
                              hipStream_t stream) {
    const float* xyz   = (const float*)d_in[0];
    const float* rot   = (const float*)d_in[1];
    const float* verts = (const float*)d_in[2];
    const float* sw    = (const float*)d_in[3];
    const float* bt    = (const float*)d_in[4];
    float* out = (float*)d_out;

    double* bfrag = (double*)d_ws;   // NT*64 doubles = 221184 B
    prep_frags_k<<<(NT * 64 + 255) / 256, 256, 0, stream>>>(verts, bfrag);
    smplnn_main<<<NBLK, 256, 0, stream>>>(xyz, rot, bfrag, sw, bt, out);
}

// Round 6
// 137.043 us; speedup vs baseline: 1.7631x; 1.5024x over previous
//
#include <hip/hip_runtime.h>
#include <math.h>

#define NPTS 65536
#define NV 6890
#define NT 432               // vertex tiles of 16 (432*16 = 6912 >= 6890)
#define VSPLIT 4             // waves per block, splitting the vertex range
#define TILES_PER_WAVE (NT / VSPLIT)   // 108
#define NJ 24
#define PTS_PER_BLK 32
#define NBLK (NPTS / PTS_PER_BLK)      // 2048

typedef double f64x4 __attribute__((ext_vector_type(4)));

// Prep: pack the B-fragment stream for v_mfma_f64_16x16x4_f64.
// frag[t*64 + l] = component (l>>4) of vertex (t*16 + (l&15));
// components: 0..2 = x,y,z (f64), 3 = ||v||^2 (exact f64 from f32 coords).
// Sentinel verts (j >= NV): (0,0,0,1e300) -> score 1e300, never selected.
__global__ void prep_frags_k(const float* __restrict__ verts, double* __restrict__ bf) {
    int e = blockIdx.x * blockDim.x + threadIdx.x;
    if (e >= NT * 64) return;
    int l = e & 63;
    int t = e >> 6;
    int j = t * 16 + (l & 15);
    int k = l >> 4;
    double val;
    if (j < NV) {
        if (k < 3) {
            val = (double)verts[3 * j + k];
        } else {
            double x = (double)verts[3 * j + 0];
            double y = (double)verts[3 * j + 1];
            double z = (double)verts[3 * j + 2];
            val = x * x + y * y + z * z;
        }
    } else {
        val = (k == 3) ? 1e300 : 0.0;
    }
    bf[e] = val;
}

__launch_bounds__(256)
__global__ void smplnn_main(const float* __restrict__ xyz,
                            const float* __restrict__ rot,
                            const double* __restrict__ bf,
                            const float* __restrict__ sw,
                            const float* __restrict__ bt,
                            float* __restrict__ out) {
    // per-wave slot boards: [wave][set][row][col]
    __shared__ double smin[VSPLIT][2][16][16];
    __shared__ int    sidv[VSPLIT][2][16][16];

    const int tid  = threadIdx.x;
    const int lane = tid & 63;
    const int wave = tid >> 6;         // vertex-split id
    const int r = lane & 15;           // M/N index within fragment
    const int k = lane >> 4;           // K index (0..3)
    const int pbase = blockIdx.x * PTS_PER_BLK;

    // A fragments (same 32 points for all 4 waves):
    // A[i][k] = (-2x_i, -2y_i, -2z_i, 1.0), i = lane&15
    double a0 = (k == 3) ? 1.0 : -2.0 * (double)xyz[3 * (pbase + r) + k];
    double a1 = (k == 3) ? 1.0 : -2.0 * (double)xyz[3 * (pbase + 16 + r) + k];

    const f64x4 zero = {0.0, 0.0, 0.0, 0.0};

    // Layout self-calibration: D = row-index and D = col-index, so the
    // (lane,reg)->(row,col) mapping of the D fragment never has to be assumed.
    double ar  = (k == 3) ? (double)r : 0.0;  // A[i][3] = i  /  B[3][j] = j
    double one = (k == 3) ? 1.0 : 0.0;        // A[i][3] = 1  /  B[3][j] = 1
    f64x4 drow = __builtin_amdgcn_mfma_f64_16x16x4f64(ar, one, zero, 0, 0, 0);
    f64x4 dcol = __builtin_amdgcn_mfma_f64_16x16x4f64(one, ar, zero, 0, 0, 0);
    int rowid[4], colid[4];
    #pragma unroll
    for (int v = 0; v < 4; ++v) { rowid[v] = (int)drow[v]; colid[v] = (int)dcol[v]; }

    double m0[4], m1[4];
    int t0[4], t1[4];
    #pragma unroll
    for (int v = 0; v < 4; ++v) { m0[v] = 1e301; m1[v] = 1e301; t0[v] = 0; t1[v] = 0; }

    // scan my quarter of the vertex tiles: s = -2 x.v + ||v||^2, exact f64 MFMA
    const int tbase = wave * TILES_PER_WAVE;
    const double* bl = bf + (size_t)tbase * 64 + lane;
    double bcur = bl[0];
    double bnx  = bl[64];
    #pragma unroll 2
    for (int t = 0; t < TILES_PER_WAVE; ++t) {
        int tp = t + 2; if (tp > TILES_PER_WAVE - 1) tp = TILES_PER_WAVE - 1;
        double bpf = bl[(size_t)tp * 64];
        f64x4 d0 = __builtin_amdgcn_mfma_f64_16x16x4f64(a0, bcur, zero, 0, 0, 0);
        f64x4 d1 = __builtin_amdgcn_mfma_f64_16x16x4f64(a1, bcur, zero, 0, 0, 0);
        #pragma unroll
        for (int v = 0; v < 4; ++v) {
            if (d0[v] < m0[v]) { m0[v] = d0[v]; t0[v] = tbase + t; }
            if (d1[v] < m1[v]) { m1[v] = d1[v]; t1[v] = tbase + t; }
        }
        bcur = bnx; bnx = bpf;
    }

    // publish slots (j = tile*16 + col)
    #pragma unroll
    for (int v = 0; v < 4; ++v) {
        smin[wave][0][rowid[v]][colid[v]] = m0[v];
        sidv[wave][0][rowid[v]][colid[v]] = t0[v] * 16 + colid[v];
        smin[wave][1][rowid[v]][colid[v]] = m1[v];
        sidv[wave][1][rowid[v]][colid[v]] = t1[v] * 16 + colid[v];
    }
    __syncthreads();

    // epilogue: wave 0, lane 0..31 -> point (set = lane>>4, row = lane&15)
    if (wave != 0 || lane >= 32) return;
    const int set  = lane >> 4;
    const int prow = lane & 15;
    const int i = pbase + set * 16 + prow;

    // merge 4 wave-boards x 16 cols; ties -> smallest vertex index
    double best = 1e302;
    int bi = 0x7fffffff;
    #pragma unroll
    for (int w = 0; w < VSPLIT; ++w) {
        #pragma unroll
        for (int c = 0; c < 16; ++c) {
            double bv = smin[w][set][prow][c];
            int bj = sidv[w][set][prow][c];
            if (bv < best || (bv == best && bj < bi)) { best = bv; bi = bj; }
        }
    }

    const float xf = xyz[3 * i + 0];
    const float yf = xyz[3 * i + 1];
    const float zf = xyz[3 * i + 2];

    // T_fwd = W[bi] @ bone_transforms(24x16)
    const float* W = &sw[bi * NJ];
    float Tm[16];
    #pragma unroll
    for (int q = 0; q < 16; ++q) Tm[q] = 0.0f;
    #pragma unroll
    for (int kk = 0; kk < NJ; ++kk) {
        float w = W[kk];
        #pragma unroll
        for (int q = 0; q < 16; ++q) Tm[q] = fmaf(w, bt[16 * kk + q], Tm[q]);
    }

    // x_bar = T[:3,:3] @ x + T[:3,3]
    float xb0 = Tm[0] * xf + Tm[1] * yf + Tm[2]  * zf + Tm[3];
    float xb1 = Tm[4] * xf + Tm[5] * yf + Tm[6]  * zf + Tm[7];
    float xb2 = Tm[8] * xf + Tm[9] * yf + Tm[10] * zf + Tm[11];

    // rotation_hat from quaternion (r,x,y,z), normalized
    float qr = rot[4 * i + 0];
    float qx = rot[4 * i + 1];
    float qy = rot[4 * i + 2];
    float qz = rot[4 * i + 3];
    float inv = 1.0f / sqrtf(qr * qr + qx * qx + qy * qy + qz * qz);
    qr *= inv; qx *= inv; qy *= inv; qz *= inv;

    float Rh[9];
    Rh[0] = 1.0f - 2.0f * (qy * qy + qz * qz);
    Rh[1] = 2.0f * (qx * qy - qr * qz);
    Rh[2] = 2.0f * (qx * qz + qr * qy);
    Rh[3] = 2.0f * (qx * qy + qr * qz);
    Rh[4] = 1.0f - 2.0f * (qx * qx + qz * qz);
    Rh[5] = 2.0f * (qy * qz - qr * qx);
    Rh[6] = 2.0f * (qx * qz - qr * qy);
    Rh[7] = 2.0f * (qy * qz + qr * qx);
    Rh[8] = 1.0f - 2.0f * (qx * qx + qy * qy);

    // rotation_bar = T[:3,:3] @ Rh
    float RB[9];
    #pragma unroll
    for (int rr = 0; rr < 3; ++rr) {
        #pragma unroll
        for (int cc = 0; cc < 3; ++cc) {
            RB[3 * rr + cc] = Tm[4 * rr + 0] * Rh[cc]
                            + Tm[4 * rr + 1] * Rh[3 + cc]
                            + Tm[4 * rr + 2] * Rh[6 + cc];
        }
    }

    // outputs: x_bar [NPTS*3] | rotation_bar [NPTS*9] | T_fwd [NPTS*16]
    out[3 * i + 0] = xb0;
    out[3 * i + 1] = xb1;
    out[3 * i + 2] = xb2;
    float* ob = out + 3 * NPTS + 9 * i;
    #pragma unroll
    for (int q = 0; q < 9; ++q) ob[q] = RB[q];
    float* ot = out + 12 * NPTS + 16 * i;
    #pragma unroll
    for (int q = 0; q < 16; ++q) ot[q] = Tm[q];
}

extern "C" void kernel_launch(void* const* d_in, const int* in_sizes, int n_in,
                              void* d_out, int out_size, void* d_ws, size_t ws_size,
                              hipStream_t stream) {
    const float* xyz   = (const float*)d_in[0];
    const float* rot   = (const float*)d_in[1];
    const float* verts = (const float*)d_in[2];
    const float* sw    = (const float*)d_in[3];
    const float* bt    = (const float*)d_in[4];
    float* out = (float*)d_out;

    double* bfrag = (double*)d_ws;   // NT*64 doubles = 221184 B
    prep_frags_k<<<(NT * 64 + 255) / 256, 256, 0, stream>>>(verts, bfrag);
    smplnn_main<<<NBLK, 256, 0, stream>>>(xyz, rot, bfrag, sw, bt, out);
}